// Round 4
// baseline (339.817 us; speedup 1.0000x reference)
//
#include <hip/hip_runtime.h>

typedef unsigned long long u64;
typedef _Float16 f16;
typedef f16 f16x8 __attribute__((ext_vector_type(8)));
typedef f16 f16x4 __attribute__((ext_vector_type(4)));
typedef float f32x4 __attribute__((ext_vector_type(4)));

#define TOK 16384
#define KK 8192
#define DD 256

#define BM 256
#define BN 256
#define BK 32
#define NT 8          // DD/BK K-tiles

#define SCALE 4096.0f                 // 2^12, exact
#define DESCALE (1.0f/8388608.0f)     // 2^-23 = 2^-24 (limb^2) * 2 (ref's 2*dot)

// ---------------- init: zero ws accumulators ----------------
__global__ void vq_init_kernel(float* __restrict__ sums, u64* __restrict__ best,
                               int* __restrict__ counts, float* __restrict__ nsum) {
    int gid = blockIdx.x * 256 + threadIdx.x;        // 2048 blocks
#pragma unroll
    for (int i = 0; i < 4; i++) {
        sums[gid + i * 524288] = 0.0f;
    }
    if (gid < TOK) best[gid] = 0xFFFFFFFFFFFFFFFFULL;
    if (gid < KK)  counts[gid] = 0;
    if (gid == 0)  *nsum = 0.0f;
}

// ---------------- e2[k] = sum_d emb[d][k]^2 (bit-identical) ----------------
__global__ void vq_e2_kernel(const float* __restrict__ emb, float* __restrict__ e2) {
    int k = blockIdx.x * 256 + threadIdx.x;
    float s = 0.0f;
    for (int d = 0; d < DD; d++) {
        float v = emb[(size_t)d * KK + k];
        s = fmaf(v, v, s);
    }
    e2[k] = s;
}

// ---------------- fused: x2[t] + fp16 limb split of x ----------------
__global__ void vq_x2split_kernel(const float* __restrict__ x, float* __restrict__ x2,
                                  f16* __restrict__ xh, f16* __restrict__ xl) {
    int t = blockIdx.x * 4 + (threadIdx.x >> 6);     // 4096 blocks, wave per token
    int lane = threadIdx.x & 63;
    size_t o = (size_t)t * DD + lane * 4;
    float4 v = *(const float4*)(x + o);
    f16x4 h, l;
    float s;
    s = v.x * SCALE; h.x = (f16)s; l.x = (f16)(s - (float)h.x);
    s = v.y * SCALE; h.y = (f16)s; l.y = (f16)(s - (float)h.y);
    s = v.z * SCALE; h.z = (f16)s; l.z = (f16)(s - (float)h.z);
    s = v.w * SCALE; h.w = (f16)s; l.w = (f16)(s - (float)h.w);
    *(f16x4*)(xh + o) = h;
    *(f16x4*)(xl + o) = l;
    float p = v.x * v.x + v.y * v.y + v.z * v.z + v.w * v.w;
#pragma unroll
    for (int off = 32; off > 0; off >>= 1) p += __shfl_down(p, off, 64);
    if (lane == 0) x2[t] = p;
}

// ---------------- transpose emb -> embT (fp32) + scaled fp16 limbs ----------------
__global__ void vq_trsplit_kernel(const float* __restrict__ emb, float* __restrict__ embT,
                                  f16* __restrict__ eh, f16* __restrict__ el) {
    __shared__ float tile[32][33];
    int tx = threadIdx.x & 31, ty = threadIdx.x >> 5;    // 32x8 threads
    int k0 = blockIdx.x * 32, d0 = blockIdx.y * 32;      // grid (256, 8)
#pragma unroll
    for (int j = 0; j < 4; j++) {
        int d = ty * 4 + j;
        tile[d][tx] = emb[(size_t)(d0 + d) * KK + k0 + tx];
    }
    __syncthreads();
#pragma unroll
    for (int j = 0; j < 4; j++) {
        int k = ty * 4 + j;
        float v = tile[tx][k];
        size_t o = (size_t)(k0 + k) * DD + d0 + tx;
        embT[o] = v;
        float sv = v * SCALE;
        f16 h = (f16)sv;
        eh[o] = h;
        el[o] = (f16)(sv - (float)h);
    }
}

// ---------------- fused distance + argmin: 256x256, 8-phase counted-vmcnt ----
// 4 phases per K-tile (C quadrants), 2 staging loads/phase, vmcnt(2) per tile
// boundary (vmcnt(0) only at tile 6). Per-cell accumulation order: per K-tile
// ascending, products hh,hl,lh — bit-identical to rounds 2/3.
__global__ __launch_bounds__(512, 2) void vq_argmin_kernel(
        const f16* __restrict__ xh, const f16* __restrict__ xl,
        const f16* __restrict__ eh, const f16* __restrict__ el,
        const float* __restrict__ x2, const float* __restrict__ e2,
        u64* __restrict__ best) {
    extern __shared__ char lds[];          // 131072: 2 bufs x {xh,xl,eh,el}[256][32]f16

    const int tid = threadIdx.x;
    const int lane = tid & 63;
    const int wid = tid >> 6;              // 8 waves: 2 (row groups) x 4 (col groups)
    const int wr = wid >> 2;               // 0..1
    const int wc = wid & 3;                // 0..3
    const int lrow = lane & 15;
    const int kg = lane >> 4;
    const int kgx = ((kg ^ ((lrow >> 1) & 3)) << 4);   // swizzled 16B slot
    const int k0 = blockIdx.x * BN;
    const int t0 = blockIdx.y * BM;

    // staging: unit u in {0:xh,1:xl,2:eh,3:el}, halves q in {0,1} (rows 0-127/128-255)
    const char* gb[4];
    gb[0] = (const char*)(xh + (size_t)t0 * DD);
    gb[1] = (const char*)(xl + (size_t)t0 * DD);
    gb[2] = (const char*)(eh + (size_t)k0 * DD);
    gb[3] = (const char*)(el + (size_t)k0 * DD);
    int goff[2];
#pragma unroll
    for (int q = 0; q < 2; q++) {
        int p = q * 8192 + tid * 16;
        int row = p >> 6;
        int slot = (p >> 4) & 3;
        int kgd = slot ^ ((row >> 1) & 3);             // pre-swizzled global source
        goff[q] = row * 512 + kgd * 16;
    }
    const int ltid = tid * 16;

#define STAGE(u, q, j, bsel)                                                              \
    __builtin_amdgcn_global_load_lds(                                                     \
        (const __attribute__((address_space(1))) unsigned int*)(gb[u] + goff[q] + (j) * 64), \
        (__attribute__((address_space(3))) unsigned int*)(lds + (bsel) * 65536 + (u) * 16384 + (q) * 8192 + ltid), \
        16, 0, 0)

    f32x4 acc[8][4];
#pragma unroll
    for (int m = 0; m < 8; m++)
#pragma unroll
        for (int n = 0; n < 4; n++) {
            f32x4 z = {0.0f, 0.0f, 0.0f, 0.0f};
            acc[m][n] = z;
        }

    // prologue: A(0) 4, B(0) 4, A(1) 4 loads; wait A(0)+B(0) (newest 4 = A(1) in flight)
    STAGE(0, 0, 0, 0); STAGE(0, 1, 0, 0); STAGE(1, 0, 0, 0); STAGE(1, 1, 0, 0);
    STAGE(2, 0, 0, 0); STAGE(2, 1, 0, 0); STAGE(3, 0, 0, 0); STAGE(3, 1, 0, 0);
    STAGE(0, 0, 1, 1); STAGE(0, 1, 1, 1); STAGE(1, 0, 1, 1); STAGE(1, 1, 1, 1);
    asm volatile("s_waitcnt vmcnt(4)" ::: "memory");
    __builtin_amdgcn_s_barrier();

    // per-thread LDS read bases (byte). A row for frag m: m*32 + wr*16 + lrow.
    const int arow = (wr * 16 + lrow) * 64 + kgx;
    const int brow = (wc * 64 + lrow) * 64 + kgx;

    f16x8 axh[4], axl[4], beh[2], bel[2];

#pragma unroll 2
    for (int j = 0; j < NT; j++) {
        char* cb = lds + (j & 1) * 65536;
        const int ob = (j & 1) ^ 1;

        // ---- phase 1: ds_read A half0 (rows 0-127) + B n-half0; stage eh(j+1) ----
#pragma unroll
        for (int m = 0; m < 4; m++) {
            axh[m] = *(const f16x8*)(cb + arow + m * 2048);
            axl[m] = *(const f16x8*)(cb + 16384 + arow + m * 2048);
        }
#pragma unroll
        for (int n = 0; n < 2; n++) {
            beh[n] = *(const f16x8*)(cb + 32768 + brow + n * 1024);
            bel[n] = *(const f16x8*)(cb + 49152 + brow + n * 1024);
        }
        if (j < 7) { STAGE(2, 0, j + 1, ob); STAGE(2, 1, j + 1, ob); }
        __builtin_amdgcn_s_barrier();
        asm volatile("s_waitcnt lgkmcnt(0)" ::: "memory");
        __builtin_amdgcn_s_setprio(1);
#pragma unroll
        for (int m = 0; m < 4; m++)
#pragma unroll
            for (int n = 0; n < 2; n++) {
                acc[m][n] = __builtin_amdgcn_mfma_f32_16x16x32_f16(axh[m], beh[n], acc[m][n], 0, 0, 0);
                acc[m][n] = __builtin_amdgcn_mfma_f32_16x16x32_f16(axh[m], bel[n], acc[m][n], 0, 0, 0);
                acc[m][n] = __builtin_amdgcn_mfma_f32_16x16x32_f16(axl[m], beh[n], acc[m][n], 0, 0, 0);
            }
        __builtin_amdgcn_s_setprio(0);
        __builtin_amdgcn_s_barrier();

        // ---- phase 2: ds_read B n-half1; stage A(j+2) half0 ----
#pragma unroll
        for (int n = 0; n < 2; n++) {
            beh[n] = *(const f16x8*)(cb + 32768 + brow + (2 + n) * 1024);
            bel[n] = *(const f16x8*)(cb + 49152 + brow + (2 + n) * 1024);
        }
        if (j < 6) { STAGE(0, 0, j + 2, j & 1); STAGE(1, 0, j + 2, j & 1); }
        __builtin_amdgcn_s_barrier();
        asm volatile("s_waitcnt lgkmcnt(0)" ::: "memory");
        __builtin_amdgcn_s_setprio(1);
#pragma unroll
        for (int m = 0; m < 4; m++)
#pragma unroll
            for (int n = 0; n < 2; n++) {
                acc[m][2 + n] = __builtin_amdgcn_mfma_f32_16x16x32_f16(axh[m], beh[n], acc[m][2 + n], 0, 0, 0);
                acc[m][2 + n] = __builtin_amdgcn_mfma_f32_16x16x32_f16(axh[m], bel[n], acc[m][2 + n], 0, 0, 0);
                acc[m][2 + n] = __builtin_amdgcn_mfma_f32_16x16x32_f16(axl[m], beh[n], acc[m][2 + n], 0, 0, 0);
            }
        __builtin_amdgcn_s_setprio(0);
        __builtin_amdgcn_s_barrier();

        // ---- phase 3: ds_read A half1 (rows 128-255); stage el(j+1) ----
#pragma unroll
        for (int m = 0; m < 4; m++) {
            axh[m] = *(const f16x8*)(cb + arow + (4 + m) * 2048);
            axl[m] = *(const f16x8*)(cb + 16384 + arow + (4 + m) * 2048);
        }
        if (j < 7) { STAGE(3, 0, j + 1, ob); STAGE(3, 1, j + 1, ob); }
        __builtin_amdgcn_s_barrier();
        asm volatile("s_waitcnt lgkmcnt(0)" ::: "memory");
        __builtin_amdgcn_s_setprio(1);
#pragma unroll
        for (int m = 0; m < 4; m++)
#pragma unroll
            for (int n = 0; n < 2; n++) {
                acc[4 + m][2 + n] = __builtin_amdgcn_mfma_f32_16x16x32_f16(axh[m], beh[n], acc[4 + m][2 + n], 0, 0, 0);
                acc[4 + m][2 + n] = __builtin_amdgcn_mfma_f32_16x16x32_f16(axh[m], bel[n], acc[4 + m][2 + n], 0, 0, 0);
                acc[4 + m][2 + n] = __builtin_amdgcn_mfma_f32_16x16x32_f16(axl[m], beh[n], acc[4 + m][2 + n], 0, 0, 0);
            }
        __builtin_amdgcn_s_setprio(0);
        __builtin_amdgcn_s_barrier();

        // ---- phase 4: ds_read B n-half0 again; stage A(j+2) half1 ----
#pragma unroll
        for (int n = 0; n < 2; n++) {
            beh[n] = *(const f16x8*)(cb + 32768 + brow + n * 1024);
            bel[n] = *(const f16x8*)(cb + 49152 + brow + n * 1024);
        }
        if (j < 6) { STAGE(0, 1, j + 2, j & 1); STAGE(1, 1, j + 2, j & 1); }
        __builtin_amdgcn_s_barrier();
        asm volatile("s_waitcnt lgkmcnt(0)" ::: "memory");
        __builtin_amdgcn_s_setprio(1);
#pragma unroll
        for (int m = 0; m < 4; m++)
#pragma unroll
            for (int n = 0; n < 2; n++) {
                acc[4 + m][n] = __builtin_amdgcn_mfma_f32_16x16x32_f16(axh[m], beh[n], acc[4 + m][n], 0, 0, 0);
                acc[4 + m][n] = __builtin_amdgcn_mfma_f32_16x16x32_f16(axh[m], bel[n], acc[4 + m][n], 0, 0, 0);
                acc[4 + m][n] = __builtin_amdgcn_mfma_f32_16x16x32_f16(axl[m], beh[n], acc[4 + m][n], 0, 0, 0);
            }
        __builtin_amdgcn_s_setprio(0);
        // tile-boundary counted wait: B(j+1)+A(j+1) landed; newest 2 (A(j+2)h1) stay out
        if (j < 6) {
            asm volatile("s_waitcnt vmcnt(2)" ::: "memory");
        } else {
            asm volatile("s_waitcnt vmcnt(0)" ::: "memory");
        }
        __builtin_amdgcn_s_barrier();
    }
#undef STAGE

    // ---------------- epilogue: distances + argmin ----------------
    // C/D: col = lane&15, row = (lane>>4)*4 + reg; frag m rows = m*32 + wr*16 + ...
    u64* red = (u64*)lds;
    if (tid < BM) red[tid] = 0xFFFFFFFFFFFFFFFFULL;
    __syncthreads();

    float se2[4];
#pragma unroll
    for (int n = 0; n < 4; n++) se2[n] = e2[k0 + wc * 64 + n * 16 + lrow];

#pragma unroll
    for (int m = 0; m < 8; m++) {
#pragma unroll
        for (int r = 0; r < 4; r++) {
            int rowl = m * 32 + wr * 16 + kg * 4 + r;
            float sx2 = x2[t0 + rowl];
            u64 b = 0xFFFFFFFFFFFFFFFFULL;
#pragma unroll
            for (int n = 0; n < 4; n++) {
                int kgl = k0 + wc * 64 + n * 16 + lrow;
                float s = sx2 + se2[n];            // rounded add (matches ref)
                float td = acc[m][n][r] * DESCALE; // exact pow2 scale
                asm volatile("" : "+v"(td));
                float dist = s - td;               // rounded sub (matches ref)
                u64 pk = ((u64)__float_as_uint(dist) << 32) | (unsigned)kgl;
                b = pk < b ? pk : b;
            }
#pragma unroll
            for (int off2 = 1; off2 < 16; off2 <<= 1) {
                u64 o = __shfl_xor(b, off2, 64);
                b = o < b ? o : b;
            }
            if (lrow == 0) atomicMin(&red[rowl], b);
        }
    }
    __syncthreads();
    if (tid < BM) atomicMin(&best[t0 + tid], red[tid]);
}

// ---------------- extract indices + counts ----------------
__global__ void vq_indices_kernel(const u64* __restrict__ best, int* __restrict__ indices,
                                  int* __restrict__ counts) {
    int t = blockIdx.x * 256 + threadIdx.x;
    int idx = (int)(best[t] & 0xFFFFFFFFULL);
    indices[t] = idx;
    atomicAdd(&counts[idx], 1);
}

// ---------------- new_N + N_sum ----------------
__global__ void vq_newN_kernel(const float* __restrict__ N, const int* __restrict__ counts,
                               float* __restrict__ outN, float* __restrict__ nsum) {
    int k = blockIdx.x * 256 + threadIdx.x;
    float a = 0.99f * N[k];
    float b = 0.01f * (float)counts[k];
    float nN = a + b;
    outN[k] = nN;
    float s = nN;
#pragma unroll
    for (int off = 32; off > 0; off >>= 1) s += __shfl_down(s, off, 64);
    __shared__ float wsum[4];
    int lane = threadIdx.x & 63, w = threadIdx.x >> 6;
    if (lane == 0) wsum[w] = s;
    __syncthreads();
    if (threadIdx.x == 0) atomicAdd(nsum, wsum[0] + wsum[1] + wsum[2] + wsum[3]);
}

// ---------------- fused: quantized_st write + sums scatter ----------------
__global__ void vq_gs_kernel(const float* __restrict__ x, const float* __restrict__ embT,
                             const int* __restrict__ indices, float* __restrict__ out0,
                             float* __restrict__ sums) {
    int t = blockIdx.x * 4 + (threadIdx.x >> 6);     // 4096 blocks, wave per token
    int lane = threadIdx.x & 63;
    int idx = indices[t];
    size_t o = (size_t)t * DD + lane * 4;
    float4 xv = *(const float4*)(x + o);
    float4 qv = *(const float4*)(embT + (size_t)idx * DD + lane * 4);
    float4 ov;
    ov.x = xv.x + (qv.x - xv.x);
    ov.y = xv.y + (qv.y - xv.y);
    ov.z = xv.z + (qv.z - xv.z);
    ov.w = xv.w + (qv.w - xv.w);
    *(float4*)(out0 + o) = ov;
    float* base = sums + (size_t)idx * DD + lane * 4;
    atomicAdd(base + 0, xv.x);
    atomicAdd(base + 1, xv.y);
    atomicAdd(base + 2, xv.z);
    atomicAdd(base + 3, xv.w);
}

// ---------------- new_m and new_embeddings ----------------
__global__ void vq_final_kernel(const float* __restrict__ m, const float* __restrict__ sums,
                                const float* __restrict__ outN, const float* __restrict__ nsum,
                                float* __restrict__ outEmb, float* __restrict__ outM) {
    int gid = blockIdx.x * 256 + threadIdx.x;
    int k = gid & (KK - 1);
    int d = gid >> 13;
    float Nsum = *nsum;
    float nN = outN[k];
    float scaled = (nN + 1e-5f) / (Nsum + 0.08192f) * Nsum;
    float a = 0.99f * m[gid];
    float b = 0.01f * sums[(size_t)k * DD + d];
    float mv = a + b;
    outM[gid] = mv;
    outEmb[gid] = mv / scaled;
}

extern "C" void kernel_launch(void* const* d_in, const int* in_sizes, int n_in,
                              void* d_out, int out_size, void* d_ws, size_t ws_size,
                              hipStream_t stream) {
    const float* x   = (const float*)d_in[0];   // [16384][256]
    const float* emb = (const float*)d_in[1];   // [256][8192]
    const float* Nin = (const float*)d_in[2];   // [8192]
    const float* min = (const float*)d_in[3];   // [256][8192]

    float* out0   = (float*)d_out;              // quantized_st  [4194304]
    float* outEmb = out0 + 4194304;             // new_embeddings [2097152]
    float* outN   = outEmb + 2097152;           // new_N [8192]
    float* outM   = outN + 8192;                // new_m [2097152]

    // workspace (floats)
    float* ws      = (float*)d_ws;
    float* sums    = ws;                        // 2097152
    float* e2buf   = ws + 2097152;              // 8192
    float* x2buf   = e2buf + 8192;              // 16384
    u64*   best    = (u64*)(x2buf + 16384);     // 16384 u64
    int*   idxbuf  = (int*)(best + 16384);      // 16384
    int*   counts  = idxbuf + 16384;            // 8192
    float* nsum    = (float*)(counts + 8192);   // 1

    // fp16 limbs + fp32 embT staged in output regions written later:
    f16* xhb = (f16*)out0;                      // 8 MB
    f16* xlb = xhb + 4194304;                   // 8 MB (out0 is 16 MB)
    f16* ehb = (f16*)outEmb;                    // 4 MB
    f16* elb = ehb + 2097152;                   // 4 MB (outEmb is 8 MB)
    float* embT = outM;                         // 8 MB, overwritten by vq_final last

    vq_init_kernel<<<2048, 256, 0, stream>>>(sums, best, counts, nsum);
    vq_e2_kernel<<<32, 256, 0, stream>>>(emb, e2buf);
    vq_x2split_kernel<<<4096, 256, 0, stream>>>(x, x2buf, xhb, xlb);
    vq_trsplit_kernel<<<dim3(256, 8), 256, 0, stream>>>(emb, embT, ehb, elb);
    vq_argmin_kernel<<<dim3(KK / BN, TOK / BM), 512, 131072, stream>>>(
        xhb, xlb, ehb, elb, x2buf, e2buf, best);
    vq_indices_kernel<<<64, 256, 0, stream>>>(best, idxbuf, counts);
    vq_newN_kernel<<<32, 256, 0, stream>>>(Nin, counts, outN, nsum);
    vq_gs_kernel<<<4096, 256, 0, stream>>>(x, embT, idxbuf, out0, sums);
    vq_final_kernel<<<8192, 256, 0, stream>>>(min, sums, outN, nsum, outEmb, outM);
}